// Round 1
// baseline (3437.372 us; speedup 1.0000x reference)
//
#include <hip/hip_runtime.h>
#include <cstdint>
#include <cstddef>

#define D 256
#define H 8
#define DFF 1024

typedef short s16x8 __attribute__((ext_vector_type(8)));
typedef float f32x4 __attribute__((ext_vector_type(4)));

static inline int cdiv(int a, int b) { return (a + b - 1) / b; }

__device__ inline uint16_t f2bf(float x) {
    unsigned u = __float_as_uint(x);
    u += 0x7FFFu + ((u >> 16) & 1u);
    return (uint16_t)(u >> 16);
}
__device__ inline float bf2f(uint16_t h) {
    return __uint_as_float(((unsigned)h) << 16);
}

__device__ inline void gload_lds16(const void* g, void* l) {
    __builtin_amdgcn_global_load_lds(
        (const __attribute__((address_space(1))) void*)g,
        (__attribute__((address_space(3))) void*)l, 16, 0, 0);
}

// ---------------------------------------------------------------------------
// CSR build (graph constant across layers)
// ---------------------------------------------------------------------------
__global__ __launch_bounds__(256) void zero_int_kernel(int* __restrict__ p, int count)
{
    int i = blockIdx.x * blockDim.x + threadIdx.x;
    if (i < count) p[i] = 0;
}

__global__ __launch_bounds__(256) void count_deg_kernel(
    const int* __restrict__ edst, int* __restrict__ deg, int E)
{
    int e = blockIdx.x * blockDim.x + threadIdx.x;
    if (e < E) atomicAdd(&deg[edst[e]], 1);
}

__global__ __launch_bounds__(256) void block_sum_kernel(
    const int* __restrict__ deg, int* __restrict__ bsum, int N)
{
    int t = threadIdx.x;
    int gid = blockIdx.x * 256 + t;
    int val = (gid < N) ? deg[gid] : 0;
    #pragma unroll
    for (int o = 1; o < 64; o <<= 1) val += __shfl_xor(val, o);
    __shared__ int r[4];
    if ((t & 63) == 0) r[t >> 6] = val;
    __syncthreads();
    if (t == 0) bsum[blockIdx.x] = r[0] + r[1] + r[2] + r[3];
}

__global__ __launch_bounds__(256) void scan_bsum_kernel(int* __restrict__ bsum, int nb)
{
    __shared__ int tmp[256];
    int t = threadIdx.x;
    int val = (t < nb) ? bsum[t] : 0;
    tmp[t] = val;
    __syncthreads();
    for (int off = 1; off < 256; off <<= 1) {
        int add = (t >= off) ? tmp[t - off] : 0;
        __syncthreads();
        tmp[t] += add;
        __syncthreads();
    }
    if (t < nb) bsum[t] = tmp[t] - val;
}

__global__ __launch_bounds__(256) void scan_write_kernel(
    const int* __restrict__ deg, const int* __restrict__ bsum,
    int* __restrict__ rowptr, int* __restrict__ cursor, int N)
{
    __shared__ int tmp[256];
    int t = threadIdx.x;
    int gid = blockIdx.x * 256 + t;
    int val = (gid < N) ? deg[gid] : 0;
    tmp[t] = val;
    __syncthreads();
    for (int off = 1; off < 256; off <<= 1) {
        int add = (t >= off) ? tmp[t - off] : 0;
        __syncthreads();
        tmp[t] += add;
        __syncthreads();
    }
    int excl = tmp[t] - val + bsum[blockIdx.x];
    if (gid < N) { rowptr[gid] = excl; cursor[gid] = excl; }
    if (gid == N - 1) rowptr[N] = excl + val;
}

__global__ __launch_bounds__(256) void fill_csr_kernel(
    const int* __restrict__ esrc, const int* __restrict__ edst,
    int* __restrict__ cursor, int* __restrict__ csr_src, int E)
{
    int e = blockIdx.x * blockDim.x + threadIdx.x;
    if (e < E) {
        int pos = atomicAdd(&cursor[edst[e]], 1);
        csr_src[pos] = esrc[e];
    }
}

// ---------------------------------------------------------------------------
// weight transpose+cast: out[c][r] = bf16(in[r][c]); per-z-slice matrices
// ---------------------------------------------------------------------------
__global__ __launch_bounds__(256) void transpose_cast_kernel(
    const float* __restrict__ in, uint16_t* __restrict__ out,
    int R, int C, size_t inLS, size_t outLS)
{
    __shared__ float t[32][33];
    in  += blockIdx.z * inLS;
    out += blockIdx.z * outLS;
    int c0 = blockIdx.x * 32, r0 = blockIdx.y * 32;
    int tx = threadIdx.x, ty = threadIdx.y;  // (32,8)
    #pragma unroll
    for (int i = 0; i < 4; ++i)
        t[ty + i * 8][tx] = in[(size_t)(r0 + ty + i * 8) * C + c0 + tx];
    __syncthreads();
    #pragma unroll
    for (int i = 0; i < 4; ++i)
        out[(size_t)(c0 + ty + i * 8) * R + r0 + tx] = f2bf(t[tx][ty + i * 8]);
}

__global__ __launch_bounds__(256) void cast_f32_bf16_kernel(
    const float* __restrict__ in, uint16_t* __restrict__ out, int n4)
{
    int i = blockIdx.x * blockDim.x + threadIdx.x;
    if (i >= n4) return;
    float4 f = ((const float4*)in)[i];
    uint16_t o0 = f2bf(f.x), o1 = f2bf(f.y), o2 = f2bf(f.z), o3 = f2bf(f.w);
    uint2 pk;
    pk.x = (unsigned)o0 | ((unsigned)o1 << 16);
    pk.y = (unsigned)o2 | ((unsigned)o3 << 16);
    ((uint2*)out)[i] = pk;
}

__global__ __launch_bounds__(256) void build_qkv_bias_kernel(
    const float* __restrict__ bq, float* __restrict__ qb, int total)
{
    int i = blockIdx.x * blockDim.x + threadIdx.x;
    if (i >= total) return;
    int l = i / 768, c = i - l * 768;
    qb[i] = (c < 256) ? bq[l * 256 + c] : 0.f;
}

// ---------------------------------------------------------------------------
// bf16 MFMA GEMM (128x128 tile): used for QKV (Nc=768) and FF1 (Nc=1024).
// Epilogue: +bias, relu opt, writes bf16 Cb.
// Bijective XCD-aware remap: each XCD gets contiguous M-tiles within one
// B-panel -> B panel resident in that XCD's private L2, A rows stream.
// ---------------------------------------------------------------------------
__global__ __launch_bounds__(256) void gemm_bf16_kernel(
    const uint16_t* __restrict__ A, int lda, int M, int K,
    const uint16_t* __restrict__ BT, int Nc,
    const float* __restrict__ bias,
    uint16_t* __restrict__ Cb, int relu)
{
    __shared__ __align__(16) uint16_t As[128 * 32];
    __shared__ __align__(16) uint16_t Bs[128 * 32];

    const int tid  = threadIdx.x;
    const int lane = tid & 63;
    const int w    = tid >> 6;
    const int wr   = w >> 1, wc = w & 1;
    const int quad = lane >> 4;
    const int l15  = lane & 15;

    // bijective XCD swizzle (m204 form): contiguous lin2 chunk per XCD,
    // m-tile fastest so a chunk shares one n-panel.
    const int nwg = gridDim.x * gridDim.y;
    const int lin = blockIdx.y * gridDim.x + blockIdx.x;
    const int xcd = lin & 7, idx = lin >> 3;
    const int q8 = nwg >> 3, r8 = nwg & 7;
    const int lin2 = (xcd < r8 ? xcd * (q8 + 1) : r8 * (q8 + 1) + (xcd - r8) * q8) + idx;
    const int mt = lin2 % gridDim.x;
    const int nt = lin2 / gridDim.x;

    const int m0 = mt * 128;
    const int n0 = nt * 128;

    f32x4 acc[4][4] = {};

    const int jbase = w * 2;
    const int srow  = lane >> 2;
    const int skc   = (lane & 3) * 8;

    for (int k0 = 0; k0 < K; k0 += 32) {
        #pragma unroll
        for (int jj = 0; jj < 2; ++jj) {
            int j = jbase + jj;
            int r = j * 16 + srow;
            int gr = m0 + r; if (gr > M - 1) gr = M - 1;
            gload_lds16(A  + (size_t)gr * lda + k0 + skc, &As[j * 512]);
            gload_lds16(BT + (size_t)(n0 + r) * K + k0 + skc, &Bs[j * 512]);
        }
        __syncthreads();

        s16x8 af[4], bf[4];
        #pragma unroll
        for (int t = 0; t < 4; ++t) {
            af[t] = *(const s16x8*)&As[(wr * 64 + t * 16 + l15) * 32 + quad * 8];
            bf[t] = *(const s16x8*)&Bs[(wc * 64 + t * 16 + l15) * 32 + quad * 8];
        }
        #pragma unroll
        for (int i = 0; i < 4; ++i)
            #pragma unroll
            for (int jt = 0; jt < 4; ++jt)
                acc[i][jt] = __builtin_amdgcn_mfma_f32_16x16x32_bf16(
                    af[i], bf[jt], acc[i][jt], 0, 0, 0);
        __syncthreads();
    }

    float bv[4];
    #pragma unroll
    for (int jt = 0; jt < 4; ++jt)
        bv[jt] = bias ? bias[n0 + wc * 64 + jt * 16 + l15] : 0.f;

    #pragma unroll
    for (int i = 0; i < 4; ++i) {
        #pragma unroll
        for (int r = 0; r < 4; ++r) {
            int m = m0 + wr * 64 + i * 16 + quad * 4 + r;
            if (m >= M) continue;
            #pragma unroll
            for (int jt = 0; jt < 4; ++jt) {
                int n = n0 + wc * 64 + jt * 16 + l15;
                float val = acc[i][jt][r] + bv[jt];
                if (relu) val = fmaxf(val, 0.f);
                Cb[(size_t)m * Nc + n] = f2bf(val);
            }
        }
    }
}

// ---------------------------------------------------------------------------
// bf16 MFMA GEMM + fused LayerNorm (Nc == 256 == one LN row per block-row).
// Tile 64Mx256N, 4 waves (each 64x64), BK=32, global_load_lds staging.
// epilogue: val = acc + bias + resid; row stats (shuffle + LDS across waves);
// out = LN(val)*g + b -> fp32 Cf (+ optional bf16 Cb shadow).
// In-place safe for resid==Cf (stats read before any write, block-local).
// ---------------------------------------------------------------------------
__global__ __launch_bounds__(256) void gemm_ln_kernel(
    const uint16_t* __restrict__ A, int lda, int M, int K,
    const uint16_t* __restrict__ BT,
    const float* __restrict__ bias,
    const float* __restrict__ resid,
    const float* __restrict__ g, const float* __restrict__ b,
    float* __restrict__ Cf, uint16_t* __restrict__ Cb)
{
    __shared__ __align__(16) uint16_t As[64 * 32];    //  4 KB
    __shared__ __align__(16) uint16_t Bs[256 * 32];   // 16 KB
    __shared__ float sS[64][4];                       //  1 KB
    __shared__ float sQ[64][4];                       //  1 KB

    const int tid  = threadIdx.x;
    const int lane = tid & 63;
    const int w    = tid >> 6;        // wave covers cols w*64..w*64+63
    const int quad = lane >> 4;
    const int l15  = lane & 15;

    const int m0 = blockIdx.x * 64;

    f32x4 acc[4][4] = {};

    for (int k0 = 0; k0 < K; k0 += 32) {
        // stage A (256 slots) + B (1024 slots), 16 B per slot, 5 slots/thread
        {
            int slot = tid;                       // A: slots 0..255
            int r = slot >> 2, kc = (slot & 3) * 8;
            int gr = m0 + r; if (gr > M - 1) gr = M - 1;
            gload_lds16(A + (size_t)gr * lda + k0 + kc, &As[slot * 8]);
        }
        #pragma unroll
        for (int i = 0; i < 4; ++i) {
            int slot = i * 256 + tid;             // B: slots 0..1023
            int n = slot >> 2, kc = (slot & 3) * 8;
            gload_lds16(BT + (size_t)n * K + k0 + kc, &Bs[slot * 8]);
        }
        __syncthreads();

        s16x8 af[4], bf[4];
        #pragma unroll
        for (int t = 0; t < 4; ++t) {
            af[t] = *(const s16x8*)&As[(t * 16 + l15) * 32 + quad * 8];
            bf[t] = *(const s16x8*)&Bs[(w * 64 + t * 16 + l15) * 32 + quad * 8];
        }
        #pragma unroll
        for (int i = 0; i < 4; ++i)
            #pragma unroll
            for (int jt = 0; jt < 4; ++jt)
                acc[i][jt] = __builtin_amdgcn_mfma_f32_16x16x32_bf16(
                    af[i], bf[jt], acc[i][jt], 0, 0, 0);
        __syncthreads();
    }

    float bv[4], gv[4], bbv[4];
    #pragma unroll
    for (int jt = 0; jt < 4; ++jt) {
        int n = w * 64 + jt * 16 + l15;
        bv[jt]  = bias[n];
        gv[jt]  = g[n];
        bbv[jt] = b[n];
    }

    // pass 1: val = acc + bias + resid (stored back into acc); row partial stats
    #pragma unroll
    for (int i = 0; i < 4; ++i) {
        #pragma unroll
        for (int r = 0; r < 4; ++r) {
            int ml = i * 16 + quad * 4 + r;       // local row 0..63
            int m  = m0 + ml;
            bool valid = (m < M);
            float s = 0.f, s2 = 0.f;
            #pragma unroll
            for (int jt = 0; jt < 4; ++jt) {
                int n = w * 64 + jt * 16 + l15;
                float val = acc[i][jt][r] + bv[jt];
                if (valid) val += resid[(size_t)m * 256 + n];
                acc[i][jt][r] = val;
                s += val;
                s2 += val * val;
            }
            #pragma unroll
            for (int o = 1; o < 16; o <<= 1) {
                s  += __shfl_xor(s, o);
                s2 += __shfl_xor(s2, o);
            }
            if (l15 == 0) { sS[ml][w] = s; sQ[ml][w] = s2; }
        }
    }
    __syncthreads();

    // pass 2: combine stats, normalize, write
    #pragma unroll
    for (int i = 0; i < 4; ++i) {
        #pragma unroll
        for (int r = 0; r < 4; ++r) {
            int ml = i * 16 + quad * 4 + r;
            int m  = m0 + ml;
            if (m >= M) continue;
            float s  = sS[ml][0] + sS[ml][1] + sS[ml][2] + sS[ml][3];
            float s2 = sQ[ml][0] + sQ[ml][1] + sQ[ml][2] + sQ[ml][3];
            float mean = s * (1.f / 256.f);
            float var  = s2 * (1.f / 256.f) - mean * mean;
            float rstd = rsqrtf(var + 1e-5f);
            #pragma unroll
            for (int jt = 0; jt < 4; ++jt) {
                int n = w * 64 + jt * 16 + l15;
                float out = (acc[i][jt][r] - mean) * rstd * gv[jt] + bbv[jt];
                Cf[(size_t)m * 256 + n] = out;
                if (Cb) Cb[(size_t)m * 256 + n] = f2bf(out);
            }
        }
    }
}

// ---------------------------------------------------------------------------
// Fused per-node attention: one wave per dst node; qkv bf16 [N][768] (q|k|v).
// ILP-4 edge unroll; wave-uniform node/src scalarized via readfirstlane so
// k/v loads use SGPR-base + lane voffset addressing (no per-lane 64-bit addr
// math); q pre-scaled by 1/sqrt(dk). fp32 accumulation; o in-place over q.
// ---------------------------------------------------------------------------
__global__ __launch_bounds__(256) void node_attn_kernel(
    uint16_t* __restrict__ qkv,
    const int* __restrict__ rowptr, const int* __restrict__ csr_src, int N)
{
    int node = (blockIdx.x * blockDim.x + threadIdx.x) >> 6;
    int lane = threadIdx.x & 63;
    if (node >= N) return;
    node = __builtin_amdgcn_readfirstlane(node);   // wave-uniform -> SGPR

    const float inv_sqrt_dk = 0.17677669529663687f;  // 1/sqrt(32)

    uint16_t* qp = qkv + (size_t)node * 768 + lane * 4;
    uint2 qu = *(const uint2*)qp;
    float q0 = bf2f((uint16_t)(qu.x & 0xFFFF)) * inv_sqrt_dk;
    float q1 = bf2f((uint16_t)(qu.x >> 16))    * inv_sqrt_dk;
    float q2 = bf2f((uint16_t)(qu.y & 0xFFFF)) * inv_sqrt_dk;
    float q3 = bf2f((uint16_t)(qu.y >> 16))    * inv_sqrt_dk;

    float a0 = 0.f, a1 = 0.f, a2 = 0.f, a3 = 0.f, zacc = 0.f;
    const int voff = lane * 4;     // element offset within a 256-slice

    int beg = rowptr[node], end = rowptr[node + 1];
    int i = beg;

    for (; i + 3 < end; i += 4) {
        int s0 = __builtin_amdgcn_readfirstlane(csr_src[i]);
        int s1 = __builtin_amdgcn_readfirstlane(csr_src[i + 1]);
        int s2 = __builtin_amdgcn_readfirstlane(csr_src[i + 2]);
        int s3 = __builtin_amdgcn_readfirstlane(csr_src[i + 3]);
        const uint16_t* b0 = qkv + (size_t)s0 * 768 + voff;
        const uint16_t* b1 = qkv + (size_t)s1 * 768 + voff;
        const uint16_t* b2 = qkv + (size_t)s2 * 768 + voff;
        const uint16_t* b3 = qkv + (size_t)s3 * 768 + voff;

        // issue all 8 loads before any use: 8 outstanding VMEM ops/wave
        uint2 ku0 = *(const uint2*)(b0 + 256);
        uint2 ku1 = *(const uint2*)(b1 + 256);
        uint2 ku2 = *(const uint2*)(b2 + 256);
        uint2 ku3 = *(const uint2*)(b3 + 256);
        uint2 vu0 = *(const uint2*)(b0 + 512);
        uint2 vu1 = *(const uint2*)(b1 + 512);
        uint2 vu2 = *(const uint2*)(b2 + 512);
        uint2 vu3 = *(const uint2*)(b3 + 512);

        float p0 = bf2f((uint16_t)(ku0.x & 0xFFFF)) * q0
                 + bf2f((uint16_t)(ku0.x >> 16))    * q1
                 + bf2f((uint16_t)(ku0.y & 0xFFFF)) * q2
                 + bf2f((uint16_t)(ku0.y >> 16))    * q3;
        float p1 = bf2f((uint16_t)(ku1.x & 0xFFFF)) * q0
                 + bf2f((uint16_t)(ku1.x >> 16))    * q1
                 + bf2f((uint16_t)(ku1.y & 0xFFFF)) * q2
                 + bf2f((uint16_t)(ku1.y >> 16))    * q3;
        float p2 = bf2f((uint16_t)(ku2.x & 0xFFFF)) * q0
                 + bf2f((uint16_t)(ku2.x >> 16))    * q1
                 + bf2f((uint16_t)(ku2.y & 0xFFFF)) * q2
                 + bf2f((uint16_t)(ku2.y >> 16))    * q3;
        float p3 = bf2f((uint16_t)(ku3.x & 0xFFFF)) * q0
                 + bf2f((uint16_t)(ku3.x >> 16))    * q1
                 + bf2f((uint16_t)(ku3.y & 0xFFFF)) * q2
                 + bf2f((uint16_t)(ku3.y >> 16))    * q3;

        p0 += __shfl_xor(p0, 1); p1 += __shfl_xor(p1, 1);
        p2 += __shfl_xor(p2, 1); p3 += __shfl_xor(p3, 1);
        p0 += __shfl_xor(p0, 2); p1 += __shfl_xor(p1, 2);
        p2 += __shfl_xor(p2, 2); p3 += __shfl_xor(p3, 2);
        p0 += __shfl_xor(p0, 4); p1 += __shfl_xor(p1, 4);
        p2 += __shfl_xor(p2, 4); p3 += __shfl_xor(p3, 4);

        float sc0 = __expf(fminf(fmaxf(p0, -5.f), 5.f));
        float sc1 = __expf(fminf(fmaxf(p1, -5.f), 5.f));
        float sc2 = __expf(fminf(fmaxf(p2, -5.f), 5.f));
        float sc3 = __expf(fminf(fmaxf(p3, -5.f), 5.f));

        a0 += bf2f((uint16_t)(vu0.x & 0xFFFF)) * sc0;
        a1 += bf2f((uint16_t)(vu0.x >> 16))    * sc0;
        a2 += bf2f((uint16_t)(vu0.y & 0xFFFF)) * sc0;
        a3 += bf2f((uint16_t)(vu0.y >> 16))    * sc0;
        zacc += sc0;
        a0 += bf2f((uint16_t)(vu1.x & 0xFFFF)) * sc1;
        a1 += bf2f((uint16_t)(vu1.x >> 16))    * sc1;
        a2 += bf2f((uint16_t)(vu1.y & 0xFFFF)) * sc1;
        a3 += bf2f((uint16_t)(vu1.y >> 16))    * sc1;
        zacc += sc1;
        a0 += bf2f((uint16_t)(vu2.x & 0xFFFF)) * sc2;
        a1 += bf2f((uint16_t)(vu2.x >> 16))    * sc2;
        a2 += bf2f((uint16_t)(vu2.y & 0xFFFF)) * sc2;
        a3 += bf2f((uint16_t)(vu2.y >> 16))    * sc2;
        zacc += sc2;
        a0 += bf2f((uint16_t)(vu3.x & 0xFFFF)) * sc3;
        a1 += bf2f((uint16_t)(vu3.x >> 16))    * sc3;
        a2 += bf2f((uint16_t)(vu3.y & 0xFFFF)) * sc3;
        a3 += bf2f((uint16_t)(vu3.y >> 16))    * sc3;
        zacc += sc3;
    }
    for (; i < end; ++i) {
        int s = __builtin_amdgcn_readfirstlane(csr_src[i]);
        const uint16_t* base = qkv + (size_t)s * 768 + voff;
        uint2 ku = *(const uint2*)(base + 256);
        uint2 vu = *(const uint2*)(base + 512);
        float p = bf2f((uint16_t)(ku.x & 0xFFFF)) * q0
                + bf2f((uint16_t)(ku.x >> 16))    * q1
                + bf2f((uint16_t)(ku.y & 0xFFFF)) * q2
                + bf2f((uint16_t)(ku.y >> 16))    * q3;
        p += __shfl_xor(p, 1);
        p += __shfl_xor(p, 2);
        p += __shfl_xor(p, 4);
        float sc = __expf(fminf(fmaxf(p, -5.f), 5.f));
        a0 += bf2f((uint16_t)(vu.x & 0xFFFF)) * sc;
        a1 += bf2f((uint16_t)(vu.x >> 16))    * sc;
        a2 += bf2f((uint16_t)(vu.y & 0xFFFF)) * sc;
        a3 += bf2f((uint16_t)(vu.y >> 16))    * sc;
        zacc += sc;
    }
    float inv = 1.f / zacc;
    uint2 pk;
    pk.x = (unsigned)f2bf(a0 * inv) | ((unsigned)f2bf(a1 * inv) << 16);
    pk.y = (unsigned)f2bf(a2 * inv) | ((unsigned)f2bf(a3 * inv) << 16);
    *(uint2*)qp = pk;
}

// ---------------------------------------------------------------------------
extern "C" void kernel_launch(void* const* d_in, const int* in_sizes, int n_in,
                              void* d_out, int out_size, void* d_ws, size_t ws_size,
                              hipStream_t stream)
{
    const float* x0   = (const float*)d_in[0];
    const int* esrc   = (const int*)d_in[1];
    const int* edst   = (const int*)d_in[2];
    const float* Wq   = (const float*)d_in[3];
    const float* bq   = (const float*)d_in[4];
    const float* Wk   = (const float*)d_in[5];
    const float* Wv   = (const float*)d_in[6];
    const float* Wo   = (const float*)d_in[7];
    const float* bo   = (const float*)d_in[8];
    const float* ln1g = (const float*)d_in[9];
    const float* ln1b = (const float*)d_in[10];
    const float* W1   = (const float*)d_in[11];
    const float* b1   = (const float*)d_in[12];
    const float* W2   = (const float*)d_in[13];
    const float* b2   = (const float*)d_in[14];
    const float* ln2g = (const float*)d_in[15];
    const float* ln2b = (const float*)d_in[16];

    const int N = in_sizes[0] / D;
    const int E = in_sizes[1];
    const int L = in_sizes[3] / (D * D);
    const size_t ND = (size_t)N * D;

    // ---- workspace layout ----
    char* p = (char*)d_ws;
    float* bufX = (float*)p;         p += ND * 4;            // fp32 residual stream
    uint16_t* xb  = (uint16_t*)p;                            // bf16 x (QKV input)
    uint16_t* t1  = xb;              p += ND * 2;            // t1 [N,1024] aliases xb+qkv
    uint16_t* qkv = (uint16_t*)p;    p += (size_t)N * 768 * 2;
    uint16_t* hb  = (uint16_t*)p;    p += ND * 2;            // bf16 h (FF1 input)
    uint16_t* BTqkv = (uint16_t*)p;  p += (size_t)L * 768 * 256 * 2;
    uint16_t* BTo   = (uint16_t*)p;  p += (size_t)L * 256 * 256 * 2;
    uint16_t* BT1   = (uint16_t*)p;  p += (size_t)L * 1024 * 256 * 2;
    uint16_t* BT2   = (uint16_t*)p;  p += (size_t)L * 256 * 1024 * 2;
    float* qbias    = (float*)p;     p += (size_t)L * 768 * 4;
    int* rowptr  = (int*)p;          p += (size_t)(N + 1) * 4;
    int* cursor  = (int*)p;          p += (size_t)N * 4;
    int* deg     = cursor;
    int* csr_src = (int*)p;          p += (size_t)E * 4;
    int* bsum    = (int*)p;

    const int nb = cdiv(N, 256);
    dim3 blk(256);
    int edgeBlocks = cdiv(E, 256);
    int nodeBlocks = cdiv(N, 4);

    // ---- one-time setup ----
    dim3 tb(32, 8);
    transpose_cast_kernel<<<dim3(8, 8, L), tb, 0, stream>>>(Wq, BTqkv, 256, 256, (size_t)65536, (size_t)768 * 256);
    transpose_cast_kernel<<<dim3(8, 8, L), tb, 0, stream>>>(Wk, BTqkv + 256 * 256, 256, 256, (size_t)65536, (size_t)768 * 256);
    transpose_cast_kernel<<<dim3(8, 8, L), tb, 0, stream>>>(Wv, BTqkv + 512 * 256, 256, 256, (size_t)65536, (size_t)768 * 256);
    transpose_cast_kernel<<<dim3(8, 8, L), tb, 0, stream>>>(Wo, BTo, 256, 256, (size_t)65536, (size_t)65536);
    transpose_cast_kernel<<<dim3(32, 8, L), tb, 0, stream>>>(W1, BT1, 256, 1024, (size_t)262144, (size_t)262144);
    transpose_cast_kernel<<<dim3(8, 32, L), tb, 0, stream>>>(W2, BT2, 1024, 256, (size_t)262144, (size_t)262144);
    build_qkv_bias_kernel<<<cdiv(L * 768, 256), blk, 0, stream>>>(bq, qbias, L * 768);
    cast_f32_bf16_kernel<<<cdiv((int)(ND / 4), 256), blk, 0, stream>>>(x0, xb, (int)(ND / 4));

    zero_int_kernel<<<cdiv(N, 256), blk, 0, stream>>>(deg, N);
    count_deg_kernel<<<edgeBlocks, blk, 0, stream>>>(edst, deg, E);
    block_sum_kernel<<<nb, blk, 0, stream>>>(deg, bsum, N);
    scan_bsum_kernel<<<1, blk, 0, stream>>>(bsum, nb);
    scan_write_kernel<<<nb, blk, 0, stream>>>(deg, bsum, rowptr, cursor, N);
    fill_csr_kernel<<<edgeBlocks, blk, 0, stream>>>(esrc, edst, cursor, csr_src, E);

    const int Mt128 = cdiv(N, 128);
    const int Mt64  = cdiv(N, 64);
    dim3 gQKV(Mt128, 768 / 128);
    dim3 gF1(Mt128, 1024 / 128);
    dim3 gLN(Mt64, 1);

    for (int l = 0; l < L; ++l) {
        const uint16_t* BTqkv_l = BTqkv + (size_t)l * 768 * 256;
        const uint16_t* BTo_l   = BTo + (size_t)l * 65536;
        const uint16_t* BT1_l   = BT1 + (size_t)l * 262144;
        const uint16_t* BT2_l   = BT2 + (size_t)l * 262144;
        const float* xin_f = (l == 0) ? x0 : bufX;

        // qkv = xb @ [Wq|Wk|Wv] + [bq|0|0]   (bf16, interleaved per node)
        gemm_bf16_kernel<<<gQKV, blk, 0, stream>>>(xb, 256, N, 256, BTqkv_l, 768,
            qbias + (size_t)l * 768, qkv, 0);

        // o (over q slice) = softmax-weighted aggregate
        node_attn_kernel<<<nodeBlocks, blk, 0, stream>>>(qkv, rowptr, csr_src, N);

        // bufX = LN1(xin + o@Wo + bo)  (fused)  -> fp32 bufX + bf16 hb
        gemm_ln_kernel<<<gLN, blk, 0, stream>>>(qkv, 768, N, 256, BTo_l,
            bo + (size_t)l * 256, xin_f, ln1g + (size_t)l * 256, ln1b + (size_t)l * 256,
            bufX, hb);

        // t1 = relu(h@W1 + b1) (bf16)
        gemm_bf16_kernel<<<gF1, blk, 0, stream>>>(hb, 256, N, 256, BT1_l, 1024,
            b1 + (size_t)l * 1024, t1, 1);

        // fout = LN2(h + t1@W2 + b2)  (fused)  -> fp32 fout + bf16 xb
        float* fout = (l == L - 1) ? (float*)d_out : bufX;
        gemm_ln_kernel<<<gLN, blk, 0, stream>>>(t1, 1024, N, 1024, BT2_l,
            b2 + (size_t)l * 256, bufX, ln2g + (size_t)l * 256, ln2b + (size_t)l * 256,
            fout, (l == L - 1) ? nullptr : xb);

        xin_f = bufX;
    }
}

// Round 2
// 3316.269 us; speedup vs baseline: 1.0365x; 1.0365x over previous
//
#include <hip/hip_runtime.h>
#include <cstdint>
#include <cstddef>

#define D 256
#define H 8
#define DFF 1024

typedef short s16x8 __attribute__((ext_vector_type(8)));
typedef float f32x4 __attribute__((ext_vector_type(4)));

static inline int cdiv(int a, int b) { return (a + b - 1) / b; }

__device__ inline uint16_t f2bf(float x) {
    unsigned u = __float_as_uint(x);
    u += 0x7FFFu + ((u >> 16) & 1u);
    return (uint16_t)(u >> 16);
}
__device__ inline float bf2f(uint16_t h) {
    return __uint_as_float(((unsigned)h) << 16);
}

__device__ inline void gload_lds16(const void* g, void* l) {
    __builtin_amdgcn_global_load_lds(
        (const __attribute__((address_space(1))) void*)g,
        (__attribute__((address_space(3))) void*)l, 16, 0, 0);
}

// ---------------------------------------------------------------------------
// CSR build (graph constant across layers)
// ---------------------------------------------------------------------------
__global__ __launch_bounds__(256) void zero_int_kernel(int* __restrict__ p, int count)
{
    int i = blockIdx.x * blockDim.x + threadIdx.x;
    if (i < count) p[i] = 0;
}

__global__ __launch_bounds__(256) void count_deg_kernel(
    const int* __restrict__ edst, int* __restrict__ deg, int E)
{
    int e = blockIdx.x * blockDim.x + threadIdx.x;
    if (e < E) atomicAdd(&deg[edst[e]], 1);
}

__global__ __launch_bounds__(256) void block_sum_kernel(
    const int* __restrict__ deg, int* __restrict__ bsum, int N)
{
    int t = threadIdx.x;
    int gid = blockIdx.x * 256 + t;
    int val = (gid < N) ? deg[gid] : 0;
    #pragma unroll
    for (int o = 1; o < 64; o <<= 1) val += __shfl_xor(val, o);
    __shared__ int r[4];
    if ((t & 63) == 0) r[t >> 6] = val;
    __syncthreads();
    if (t == 0) bsum[blockIdx.x] = r[0] + r[1] + r[2] + r[3];
}

__global__ __launch_bounds__(256) void scan_bsum_kernel(int* __restrict__ bsum, int nb)
{
    __shared__ int tmp[256];
    int t = threadIdx.x;
    int val = (t < nb) ? bsum[t] : 0;
    tmp[t] = val;
    __syncthreads();
    for (int off = 1; off < 256; off <<= 1) {
        int add = (t >= off) ? tmp[t - off] : 0;
        __syncthreads();
        tmp[t] += add;
        __syncthreads();
    }
    if (t < nb) bsum[t] = tmp[t] - val;
}

__global__ __launch_bounds__(256) void scan_write_kernel(
    const int* __restrict__ deg, const int* __restrict__ bsum,
    int* __restrict__ rowptr, int* __restrict__ cursor, int N)
{
    __shared__ int tmp[256];
    int t = threadIdx.x;
    int gid = blockIdx.x * 256 + t;
    int val = (gid < N) ? deg[gid] : 0;
    tmp[t] = val;
    __syncthreads();
    for (int off = 1; off < 256; off <<= 1) {
        int add = (t >= off) ? tmp[t - off] : 0;
        __syncthreads();
        tmp[t] += add;
        __syncthreads();
    }
    int excl = tmp[t] - val + bsum[blockIdx.x];
    if (gid < N) { rowptr[gid] = excl; cursor[gid] = excl; }
    if (gid == N - 1) rowptr[N] = excl + val;
}

__global__ __launch_bounds__(256) void fill_csr_kernel(
    const int* __restrict__ esrc, const int* __restrict__ edst,
    int* __restrict__ cursor, int* __restrict__ csr_src, int E)
{
    int e = blockIdx.x * blockDim.x + threadIdx.x;
    if (e < E) {
        int pos = atomicAdd(&cursor[edst[e]], 1);
        csr_src[pos] = esrc[e];
    }
}

// ---------------------------------------------------------------------------
// weight transpose+cast: out[c][r] = bf16(in[r][c]); per-z-slice matrices
// ---------------------------------------------------------------------------
__global__ __launch_bounds__(256) void transpose_cast_kernel(
    const float* __restrict__ in, uint16_t* __restrict__ out,
    int R, int C, size_t inLS, size_t outLS)
{
    __shared__ float t[32][33];
    in  += blockIdx.z * inLS;
    out += blockIdx.z * outLS;
    int c0 = blockIdx.x * 32, r0 = blockIdx.y * 32;
    int tx = threadIdx.x, ty = threadIdx.y;  // (32,8)
    #pragma unroll
    for (int i = 0; i < 4; ++i)
        t[ty + i * 8][tx] = in[(size_t)(r0 + ty + i * 8) * C + c0 + tx];
    __syncthreads();
    #pragma unroll
    for (int i = 0; i < 4; ++i)
        out[(size_t)(c0 + ty + i * 8) * R + r0 + tx] = f2bf(t[tx][ty + i * 8]);
}

__global__ __launch_bounds__(256) void cast_f32_bf16_kernel(
    const float* __restrict__ in, uint16_t* __restrict__ out, int n4)
{
    int i = blockIdx.x * blockDim.x + threadIdx.x;
    if (i >= n4) return;
    float4 f = ((const float4*)in)[i];
    uint16_t o0 = f2bf(f.x), o1 = f2bf(f.y), o2 = f2bf(f.z), o3 = f2bf(f.w);
    uint2 pk;
    pk.x = (unsigned)o0 | ((unsigned)o1 << 16);
    pk.y = (unsigned)o2 | ((unsigned)o3 << 16);
    ((uint2*)out)[i] = pk;
}

__global__ __launch_bounds__(256) void build_qkv_bias_kernel(
    const float* __restrict__ bq, float* __restrict__ qb, int total)
{
    int i = blockIdx.x * blockDim.x + threadIdx.x;
    if (i >= total) return;
    int l = i / 768, c = i - l * 768;
    qb[i] = (c < 256) ? bq[l * 256 + c] : 0.f;
}

// ---------------------------------------------------------------------------
// bf16 MFMA GEMM (128x128 tile): used for QKV (Nc=768).
// Epilogue: +bias, relu opt, writes bf16 Cb. Bijective XCD-aware remap.
// ---------------------------------------------------------------------------
__global__ __launch_bounds__(256) void gemm_bf16_kernel(
    const uint16_t* __restrict__ A, int lda, int M, int K,
    const uint16_t* __restrict__ BT, int Nc,
    const float* __restrict__ bias,
    uint16_t* __restrict__ Cb, int relu)
{
    __shared__ __align__(16) uint16_t As[128 * 32];
    __shared__ __align__(16) uint16_t Bs[128 * 32];

    const int tid  = threadIdx.x;
    const int lane = tid & 63;
    const int w    = tid >> 6;
    const int wr   = w >> 1, wc = w & 1;
    const int quad = lane >> 4;
    const int l15  = lane & 15;

    const int nwg = gridDim.x * gridDim.y;
    const int lin = blockIdx.y * gridDim.x + blockIdx.x;
    const int xcd = lin & 7, idx = lin >> 3;
    const int q8 = nwg >> 3, r8 = nwg & 7;
    const int lin2 = (xcd < r8 ? xcd * (q8 + 1) : r8 * (q8 + 1) + (xcd - r8) * q8) + idx;
    const int mt = lin2 % gridDim.x;
    const int nt = lin2 / gridDim.x;

    const int m0 = mt * 128;
    const int n0 = nt * 128;

    f32x4 acc[4][4] = {};

    const int jbase = w * 2;
    const int srow  = lane >> 2;
    const int skc   = (lane & 3) * 8;

    for (int k0 = 0; k0 < K; k0 += 32) {
        #pragma unroll
        for (int jj = 0; jj < 2; ++jj) {
            int j = jbase + jj;
            int r = j * 16 + srow;
            int gr = m0 + r; if (gr > M - 1) gr = M - 1;
            gload_lds16(A  + (size_t)gr * lda + k0 + skc, &As[j * 512]);
            gload_lds16(BT + (size_t)(n0 + r) * K + k0 + skc, &Bs[j * 512]);
        }
        __syncthreads();

        s16x8 af[4], bf[4];
        #pragma unroll
        for (int t = 0; t < 4; ++t) {
            af[t] = *(const s16x8*)&As[(wr * 64 + t * 16 + l15) * 32 + quad * 8];
            bf[t] = *(const s16x8*)&Bs[(wc * 64 + t * 16 + l15) * 32 + quad * 8];
        }
        #pragma unroll
        for (int i = 0; i < 4; ++i)
            #pragma unroll
            for (int jt = 0; jt < 4; ++jt)
                acc[i][jt] = __builtin_amdgcn_mfma_f32_16x16x32_bf16(
                    af[i], bf[jt], acc[i][jt], 0, 0, 0);
        __syncthreads();
    }

    float bv[4];
    #pragma unroll
    for (int jt = 0; jt < 4; ++jt)
        bv[jt] = bias ? bias[n0 + wc * 64 + jt * 16 + l15] : 0.f;

    #pragma unroll
    for (int i = 0; i < 4; ++i) {
        #pragma unroll
        for (int r = 0; r < 4; ++r) {
            int m = m0 + wr * 64 + i * 16 + quad * 4 + r;
            if (m >= M) continue;
            #pragma unroll
            for (int jt = 0; jt < 4; ++jt) {
                int n = n0 + wc * 64 + jt * 16 + l15;
                float val = acc[i][jt][r] + bv[jt];
                if (relu) val = fmaxf(val, 0.f);
                Cb[(size_t)m * Nc + n] = f2bf(val);
            }
        }
    }
}

// ---------------------------------------------------------------------------
// bf16 MFMA GEMM + fused LayerNorm (Nc == 256). Tile 64Mx256N, 4 waves.
// ---------------------------------------------------------------------------
__global__ __launch_bounds__(256) void gemm_ln_kernel(
    const uint16_t* __restrict__ A, int lda, int M, int K,
    const uint16_t* __restrict__ BT,
    const float* __restrict__ bias,
    const float* __restrict__ resid,
    const float* __restrict__ g, const float* __restrict__ b,
    float* __restrict__ Cf, uint16_t* __restrict__ Cb)
{
    __shared__ __align__(16) uint16_t As[64 * 32];    //  4 KB
    __shared__ __align__(16) uint16_t Bs[256 * 32];   // 16 KB
    __shared__ float sS[64][4];                       //  1 KB
    __shared__ float sQ[64][4];                       //  1 KB

    const int tid  = threadIdx.x;
    const int lane = tid & 63;
    const int w    = tid >> 6;        // wave covers cols w*64..w*64+63
    const int quad = lane >> 4;
    const int l15  = lane & 15;

    const int m0 = blockIdx.x * 64;

    f32x4 acc[4][4] = {};

    for (int k0 = 0; k0 < K; k0 += 32) {
        {
            int slot = tid;                       // A: slots 0..255
            int r = slot >> 2, kc = (slot & 3) * 8;
            int gr = m0 + r; if (gr > M - 1) gr = M - 1;
            gload_lds16(A + (size_t)gr * lda + k0 + kc, &As[slot * 8]);
        }
        #pragma unroll
        for (int i = 0; i < 4; ++i) {
            int slot = i * 256 + tid;             // B: slots 0..1023
            int n = slot >> 2, kc = (slot & 3) * 8;
            gload_lds16(BT + (size_t)n * K + k0 + kc, &Bs[slot * 8]);
        }
        __syncthreads();

        s16x8 af[4], bf[4];
        #pragma unroll
        for (int t = 0; t < 4; ++t) {
            af[t] = *(const s16x8*)&As[(t * 16 + l15) * 32 + quad * 8];
            bf[t] = *(const s16x8*)&Bs[(w * 64 + t * 16 + l15) * 32 + quad * 8];
        }
        #pragma unroll
        for (int i = 0; i < 4; ++i)
            #pragma unroll
            for (int jt = 0; jt < 4; ++jt)
                acc[i][jt] = __builtin_amdgcn_mfma_f32_16x16x32_bf16(
                    af[i], bf[jt], acc[i][jt], 0, 0, 0);
        __syncthreads();
    }

    float bv[4], gv[4], bbv[4];
    #pragma unroll
    for (int jt = 0; jt < 4; ++jt) {
        int n = w * 64 + jt * 16 + l15;
        bv[jt]  = bias[n];
        gv[jt]  = g[n];
        bbv[jt] = b[n];
    }

    #pragma unroll
    for (int i = 0; i < 4; ++i) {
        #pragma unroll
        for (int r = 0; r < 4; ++r) {
            int ml = i * 16 + quad * 4 + r;       // local row 0..63
            int m  = m0 + ml;
            bool valid = (m < M);
            float s = 0.f, s2 = 0.f;
            #pragma unroll
            for (int jt = 0; jt < 4; ++jt) {
                int n = w * 64 + jt * 16 + l15;
                float val = acc[i][jt][r] + bv[jt];
                if (valid) val += resid[(size_t)m * 256 + n];
                acc[i][jt][r] = val;
                s += val;
                s2 += val * val;
            }
            #pragma unroll
            for (int o = 1; o < 16; o <<= 1) {
                s  += __shfl_xor(s, o);
                s2 += __shfl_xor(s2, o);
            }
            if (l15 == 0) { sS[ml][w] = s; sQ[ml][w] = s2; }
        }
    }
    __syncthreads();

    #pragma unroll
    for (int i = 0; i < 4; ++i) {
        #pragma unroll
        for (int r = 0; r < 4; ++r) {
            int ml = i * 16 + quad * 4 + r;
            int m  = m0 + ml;
            if (m >= M) continue;
            float s  = sS[ml][0] + sS[ml][1] + sS[ml][2] + sS[ml][3];
            float s2 = sQ[ml][0] + sQ[ml][1] + sQ[ml][2] + sQ[ml][3];
            float mean = s * (1.f / 256.f);
            float var  = s2 * (1.f / 256.f) - mean * mean;
            float rstd = rsqrtf(var + 1e-5f);
            #pragma unroll
            for (int jt = 0; jt < 4; ++jt) {
                int n = w * 64 + jt * 16 + l15;
                float out = (acc[i][jt][r] - mean) * rstd * gv[jt] + bbv[jt];
                Cf[(size_t)m * 256 + n] = out;
                if (Cb) Cb[(size_t)m * 256 + n] = f2bf(out);
            }
        }
    }
}

// ---------------------------------------------------------------------------
// Fused FFN: out = LN2(resid + relu(h@W1 + b1)@W2 + b2).
// Per block: 64 rows. 8 chunks of DFF=128:
//   GEMM1 (h[64,256] @ W1chunk -> T[64,128], relu+b1, bf16 -> Ts LDS)
//   GEMM2 (Ts @ W2chunk accumulated into persistent acc2[64,256])
// then gemm_ln-style LN epilogue. t1 never touches global memory.
// W1+W2 = 1 MB/layer -> L2-resident on every XCD.
// LDS 38 KB -> 3-4 blocks/CU.
// ---------------------------------------------------------------------------
__global__ __launch_bounds__(256) void ffn_fused_kernel(
    const uint16_t* __restrict__ A,      // hb [M][256] bf16
    int M,
    const uint16_t* __restrict__ BT1,    // W1^T [1024][256] bf16
    const float* __restrict__ b1,        // [1024]
    const uint16_t* __restrict__ BT2,    // W2^T [256][1024] bf16
    const float* __restrict__ b2,        // [256]
    const float* __restrict__ resid,     // [M][256] fp32
    const float* __restrict__ g, const float* __restrict__ b,
    float* __restrict__ Cf, uint16_t* __restrict__ Cb)
{
    __shared__ __align__(16) uint16_t As[64 * 32];     //  4 KB
    __shared__ __align__(16) uint16_t Bs[256 * 32];    // 16 KB
    __shared__ __align__(16) uint16_t Ts[64 * 128];    // 16 KB (4 subtiles [64][32])
    __shared__ float sS[64][4];                        //  1 KB
    __shared__ float sQ[64][4];                        //  1 KB

    const int tid  = threadIdx.x;
    const int lane = tid & 63;
    const int w    = tid >> 6;       // wave: T cols w*32..+32 (GEMM1), out cols w*64..+64 (GEMM2)
    const int quad = lane >> 4;
    const int l15  = lane & 15;
    const int m0   = blockIdx.x * 64;

    f32x4 acc2[4][4] = {};

    for (int c = 0; c < 8; ++c) {
        f32x4 acc1[4][2] = {};

        // ---- GEMM1: T = h @ W1[:, c*128 .. c*128+128) ----
        for (int k0 = 0; k0 < 256; k0 += 32) {
            {   // A slice [64][32]: 256 slots, 1/thread
                int r = tid >> 2, kc = (tid & 3) * 8;
                int gr = m0 + r; if (gr > M - 1) gr = M - 1;
                gload_lds16(A + (size_t)gr * 256 + k0 + kc, &As[tid * 8]);
            }
            #pragma unroll
            for (int i = 0; i < 2; ++i) {   // B1 slice [128][32]: 512 slots, 2/thread
                int slot = i * 256 + tid;
                int n = slot >> 2, kc = (slot & 3) * 8;
                gload_lds16(BT1 + (size_t)(c * 128 + n) * 256 + k0 + kc, &Bs[slot * 8]);
            }
            __syncthreads();

            s16x8 af[4], bf1[2];
            #pragma unroll
            for (int t = 0; t < 4; ++t)
                af[t] = *(const s16x8*)&As[(t * 16 + l15) * 32 + quad * 8];
            #pragma unroll
            for (int jt = 0; jt < 2; ++jt)
                bf1[jt] = *(const s16x8*)&Bs[(w * 32 + jt * 16 + l15) * 32 + quad * 8];
            #pragma unroll
            for (int i = 0; i < 4; ++i)
                #pragma unroll
                for (int jt = 0; jt < 2; ++jt)
                    acc1[i][jt] = __builtin_amdgcn_mfma_f32_16x16x32_bf16(
                        af[i], bf1[jt], acc1[i][jt], 0, 0, 0);
            __syncthreads();
        }

        // ---- T epilogue: +b1, relu, bf16 -> Ts (wave-private region) ----
        float bv1[2];
        #pragma unroll
        for (int jt = 0; jt < 2; ++jt)
            bv1[jt] = b1[c * 128 + w * 32 + jt * 16 + l15];
        #pragma unroll
        for (int i = 0; i < 4; ++i)
            #pragma unroll
            for (int r = 0; r < 4; ++r) {
                int ml = i * 16 + quad * 4 + r;
                #pragma unroll
                for (int jt = 0; jt < 2; ++jt) {
                    float val = acc1[i][jt][r] + bv1[jt];
                    val = fmaxf(val, 0.f);
                    Ts[w * 2048 + ml * 32 + jt * 16 + l15] = f2bf(val);
                }
            }
        __syncthreads();   // Ts visible to all waves

        // ---- GEMM2: acc2 += T @ W2[c*128 .. +128, :] ----
        for (int ts = 0; ts < 4; ++ts) {
            #pragma unroll
            for (int i = 0; i < 4; ++i) {   // B2 slice [256][32]: 1024 slots, 4/thread
                int slot = i * 256 + tid;
                int n = slot >> 2, kc = (slot & 3) * 8;
                gload_lds16(BT2 + (size_t)n * 1024 + c * 128 + ts * 32 + kc, &Bs[slot * 8]);
            }
            __syncthreads();

            s16x8 af2[4], bf2[4];
            #pragma unroll
            for (int i = 0; i < 4; ++i)
                af2[i] = *(const s16x8*)&Ts[ts * 2048 + (i * 16 + l15) * 32 + quad * 8];
            #pragma unroll
            for (int jt = 0; jt < 4; ++jt)
                bf2[jt] = *(const s16x8*)&Bs[(w * 64 + jt * 16 + l15) * 32 + quad * 8];
            #pragma unroll
            for (int i = 0; i < 4; ++i)
                #pragma unroll
                for (int jt = 0; jt < 4; ++jt)
                    acc2[i][jt] = __builtin_amdgcn_mfma_f32_16x16x32_bf16(
                        af2[i], bf2[jt], acc2[i][jt], 0, 0, 0);
            __syncthreads();
        }
    }

    // ---- LN epilogue (identical to gemm_ln) ----
    float bv[4], gv[4], bbv[4];
    #pragma unroll
    for (int jt = 0; jt < 4; ++jt) {
        int n = w * 64 + jt * 16 + l15;
        bv[jt]  = b2[n];
        gv[jt]  = g[n];
        bbv[jt] = b[n];
    }

    #pragma unroll
    for (int i = 0; i < 4; ++i) {
        #pragma unroll
        for (int r = 0; r < 4; ++r) {
            int ml = i * 16 + quad * 4 + r;
            int m  = m0 + ml;
            bool valid = (m < M);
            float s = 0.f, s2 = 0.f;
            #pragma unroll
            for (int jt = 0; jt < 4; ++jt) {
                int n = w * 64 + jt * 16 + l15;
                float val = acc2[i][jt][r] + bv[jt];
                if (valid) val += resid[(size_t)m * 256 + n];
                acc2[i][jt][r] = val;
                s += val;
                s2 += val * val;
            }
            #pragma unroll
            for (int o = 1; o < 16; o <<= 1) {
                s  += __shfl_xor(s, o);
                s2 += __shfl_xor(s2, o);
            }
            if (l15 == 0) { sS[ml][w] = s; sQ[ml][w] = s2; }
        }
    }
    __syncthreads();

    #pragma unroll
    for (int i = 0; i < 4; ++i) {
        #pragma unroll
        for (int r = 0; r < 4; ++r) {
            int ml = i * 16 + quad * 4 + r;
            int m  = m0 + ml;
            if (m >= M) continue;
            float s  = sS[ml][0] + sS[ml][1] + sS[ml][2] + sS[ml][3];
            float s2 = sQ[ml][0] + sQ[ml][1] + sQ[ml][2] + sQ[ml][3];
            float mean = s * (1.f / 256.f);
            float var  = s2 * (1.f / 256.f) - mean * mean;
            float rstd = rsqrtf(var + 1e-5f);
            #pragma unroll
            for (int jt = 0; jt < 4; ++jt) {
                int n = w * 64 + jt * 16 + l15;
                float out = (acc2[i][jt][r] - mean) * rstd * gv[jt] + bbv[jt];
                Cf[(size_t)m * 256 + n] = out;
                if (Cb) Cb[(size_t)m * 256 + n] = f2bf(out);
            }
        }
    }
}

// ---------------------------------------------------------------------------
// Fused per-node attention: one wave per dst node; qkv bf16 [N][768] (q|k|v).
// ILP-2 edge unroll; fp32 accumulation; o in-place over q slice.
// (Reverted to r0 body: gather is memory-system-bound; ILP-4+scalarize
//  regressed 113->118 us.)
// ---------------------------------------------------------------------------
__global__ __launch_bounds__(256) void node_attn_kernel(
    uint16_t* __restrict__ qkv,
    const int* __restrict__ rowptr, const int* __restrict__ csr_src, int N)
{
    int node = (blockIdx.x * blockDim.x + threadIdx.x) >> 6;
    int lane = threadIdx.x & 63;
    if (node >= N) return;

    uint16_t* qp = qkv + (size_t)node * 768 + lane * 4;
    uint2 qu = *(const uint2*)qp;
    float q0 = bf2f((uint16_t)(qu.x & 0xFFFF)), q1 = bf2f((uint16_t)(qu.x >> 16));
    float q2 = bf2f((uint16_t)(qu.y & 0xFFFF)), q3 = bf2f((uint16_t)(qu.y >> 16));

    float a0 = 0.f, a1 = 0.f, a2 = 0.f, a3 = 0.f, zacc = 0.f;
    const float inv_sqrt_dk = 0.17677669529663687f;  // 1/sqrt(32)

    int beg = rowptr[node], end = rowptr[node + 1];
    int i = beg;
    for (; i + 1 < end; i += 2) {
        int s0 = csr_src[i], s1 = csr_src[i + 1];
        const uint16_t* b0 = qkv + (size_t)s0 * 768;
        const uint16_t* b1 = qkv + (size_t)s1 * 768;
        uint2 ku0 = *(const uint2*)(b0 + 256 + lane * 4);
        uint2 ku1 = *(const uint2*)(b1 + 256 + lane * 4);
        uint2 vu0 = *(const uint2*)(b0 + 512 + lane * 4);
        uint2 vu1 = *(const uint2*)(b1 + 512 + lane * 4);

        float p0 = bf2f((uint16_t)(ku0.x & 0xFFFF)) * q0
                 + bf2f((uint16_t)(ku0.x >> 16))   * q1
                 + bf2f((uint16_t)(ku0.y & 0xFFFF)) * q2
                 + bf2f((uint16_t)(ku0.y >> 16))   * q3;
        float p1 = bf2f((uint16_t)(ku1.x & 0xFFFF)) * q0
                 + bf2f((uint16_t)(ku1.x >> 16))   * q1
                 + bf2f((uint16_t)(ku1.y & 0xFFFF)) * q2
                 + bf2f((uint16_t)(ku1.y >> 16))   * q3;
        p0 += __shfl_xor(p0, 1); p1 += __shfl_xor(p1, 1);
        p0 += __shfl_xor(p0, 2); p1 += __shfl_xor(p1, 2);
        p0 += __shfl_xor(p0, 4); p1 += __shfl_xor(p1, 4);
        float sc0 = __expf(fminf(fmaxf(p0 * inv_sqrt_dk, -5.f), 5.f));
        float sc1 = __expf(fminf(fmaxf(p1 * inv_sqrt_dk, -5.f), 5.f));

        a0 += bf2f((uint16_t)(vu0.x & 0xFFFF)) * sc0;
        a1 += bf2f((uint16_t)(vu0.x >> 16))   * sc0;
        a2 += bf2f((uint16_t)(vu0.y & 0xFFFF)) * sc0;
        a3 += bf2f((uint16_t)(vu0.y >> 16))   * sc0;
        zacc += sc0;
        a0 += bf2f((uint16_t)(vu1.x & 0xFFFF)) * sc1;
        a1 += bf2f((uint16_t)(vu1.x >> 16))   * sc1;
        a2 += bf2f((uint16_t)(vu1.y & 0xFFFF)) * sc1;
        a3 += bf2f((uint16_t)(vu1.y >> 16))   * sc1;
        zacc += sc1;
    }
    if (i < end) {
        int s = csr_src[i];
        const uint16_t* base = qkv + (size_t)s * 768;
        uint2 ku = *(const uint2*)(base + 256 + lane * 4);
        float p = bf2f((uint16_t)(ku.x & 0xFFFF)) * q0
                + bf2f((uint16_t)(ku.x >> 16))   * q1
                + bf2f((uint16_t)(ku.y & 0xFFFF)) * q2
                + bf2f((uint16_t)(ku.y >> 16))   * q3;
        p += __shfl_xor(p, 1);
        p += __shfl_xor(p, 2);
        p += __shfl_xor(p, 4);
        float sc = __expf(fminf(fmaxf(p * inv_sqrt_dk, -5.f), 5.f));
        uint2 vu = *(const uint2*)(base + 512 + lane * 4);
        a0 += bf2f((uint16_t)(vu.x & 0xFFFF)) * sc;
        a1 += bf2f((uint16_t)(vu.x >> 16))   * sc;
        a2 += bf2f((uint16_t)(vu.y & 0xFFFF)) * sc;
        a3 += bf2f((uint16_t)(vu.y >> 16))   * sc;
        zacc += sc;
    }
    float inv = 1.f / zacc;
    uint2 pk;
    pk.x = (unsigned)f2bf(a0 * inv) | ((unsigned)f2bf(a1 * inv) << 16);
    pk.y = (unsigned)f2bf(a2 * inv) | ((unsigned)f2bf(a3 * inv) << 16);
    *(uint2*)qp = pk;
}

// ---------------------------------------------------------------------------
extern "C" void kernel_launch(void* const* d_in, const int* in_sizes, int n_in,
                              void* d_out, int out_size, void* d_ws, size_t ws_size,
                              hipStream_t stream)
{
    const float* x0   = (const float*)d_in[0];
    const int* esrc   = (const int*)d_in[1];
    const int* edst   = (const int*)d_in[2];
    const float* Wq   = (const float*)d_in[3];
    const float* bq   = (const float*)d_in[4];
    const float* Wk   = (const float*)d_in[5];
    const float* Wv   = (const float*)d_in[6];
    const float* Wo   = (const float*)d_in[7];
    const float* bo   = (const float*)d_in[8];
    const float* ln1g = (const float*)d_in[9];
    const float* ln1b = (const float*)d_in[10];
    const float* W1   = (const float*)d_in[11];
    const float* b1   = (const float*)d_in[12];
    const float* W2   = (const float*)d_in[13];
    const float* b2   = (const float*)d_in[14];
    const float* ln2g = (const float*)d_in[15];
    const float* ln2b = (const float*)d_in[16];

    const int N = in_sizes[0] / D;
    const int E = in_sizes[1];
    const int L = in_sizes[3] / (D * D);
    const size_t ND = (size_t)N * D;

    // ---- workspace layout ----
    char* p = (char*)d_ws;
    float* bufX = (float*)p;         p += ND * 4;            // fp32 residual stream
    uint16_t* xb  = (uint16_t*)p;                            // bf16 x (QKV input)
    uint16_t* t1  = xb;              p += ND * 2;            // alias (t1 no longer used)
    uint16_t* qkv = (uint16_t*)p;    p += (size_t)N * 768 * 2;
    uint16_t* hb  = (uint16_t*)p;    p += ND * 2;            // bf16 h (FFN input)
    uint16_t* BTqkv = (uint16_t*)p;  p += (size_t)L * 768 * 256 * 2;
    uint16_t* BTo   = (uint16_t*)p;  p += (size_t)L * 256 * 256 * 2;
    uint16_t* BT1   = (uint16_t*)p;  p += (size_t)L * 1024 * 256 * 2;
    uint16_t* BT2   = (uint16_t*)p;  p += (size_t)L * 256 * 1024 * 2;
    float* qbias    = (float*)p;     p += (size_t)L * 768 * 4;
    int* rowptr  = (int*)p;          p += (size_t)(N + 1) * 4;
    int* cursor  = (int*)p;          p += (size_t)N * 4;
    int* deg     = cursor;
    int* csr_src = (int*)p;          p += (size_t)E * 4;
    int* bsum    = (int*)p;
    (void)t1;

    const int nb = cdiv(N, 256);
    dim3 blk(256);
    int edgeBlocks = cdiv(E, 256);
    int nodeBlocks = cdiv(N, 4);

    // ---- one-time setup ----
    dim3 tb(32, 8);
    transpose_cast_kernel<<<dim3(8, 8, L), tb, 0, stream>>>(Wq, BTqkv, 256, 256, (size_t)65536, (size_t)768 * 256);
    transpose_cast_kernel<<<dim3(8, 8, L), tb, 0, stream>>>(Wk, BTqkv + 256 * 256, 256, 256, (size_t)65536, (size_t)768 * 256);
    transpose_cast_kernel<<<dim3(8, 8, L), tb, 0, stream>>>(Wv, BTqkv + 512 * 256, 256, 256, (size_t)65536, (size_t)768 * 256);
    transpose_cast_kernel<<<dim3(8, 8, L), tb, 0, stream>>>(Wo, BTo, 256, 256, (size_t)65536, (size_t)65536);
    transpose_cast_kernel<<<dim3(32, 8, L), tb, 0, stream>>>(W1, BT1, 256, 1024, (size_t)262144, (size_t)262144);
    transpose_cast_kernel<<<dim3(8, 32, L), tb, 0, stream>>>(W2, BT2, 1024, 256, (size_t)262144, (size_t)262144);
    build_qkv_bias_kernel<<<cdiv(L * 768, 256), blk, 0, stream>>>(bq, qbias, L * 768);
    cast_f32_bf16_kernel<<<cdiv((int)(ND / 4), 256), blk, 0, stream>>>(x0, xb, (int)(ND / 4));

    zero_int_kernel<<<cdiv(N, 256), blk, 0, stream>>>(deg, N);
    count_deg_kernel<<<edgeBlocks, blk, 0, stream>>>(edst, deg, E);
    block_sum_kernel<<<nb, blk, 0, stream>>>(deg, bsum, N);
    scan_bsum_kernel<<<1, blk, 0, stream>>>(bsum, nb);
    scan_write_kernel<<<nb, blk, 0, stream>>>(deg, bsum, rowptr, cursor, N);
    fill_csr_kernel<<<edgeBlocks, blk, 0, stream>>>(esrc, edst, cursor, csr_src, E);

    const int Mt128 = cdiv(N, 128);
    const int Mt64  = cdiv(N, 64);
    dim3 gQKV(Mt128, 768 / 128);
    dim3 gLN(Mt64, 1);

    for (int l = 0; l < L; ++l) {
        const uint16_t* BTqkv_l = BTqkv + (size_t)l * 768 * 256;
        const uint16_t* BTo_l   = BTo + (size_t)l * 65536;
        const uint16_t* BT1_l   = BT1 + (size_t)l * 262144;
        const uint16_t* BT2_l   = BT2 + (size_t)l * 262144;
        const float* xin_f = (l == 0) ? x0 : bufX;

        // qkv = xb @ [Wq|Wk|Wv] + [bq|0|0]   (bf16, interleaved per node)
        gemm_bf16_kernel<<<gQKV, blk, 0, stream>>>(xb, 256, N, 256, BTqkv_l, 768,
            qbias + (size_t)l * 768, qkv, 0);

        // o (over q slice) = softmax-weighted aggregate
        node_attn_kernel<<<nodeBlocks, blk, 0, stream>>>(qkv, rowptr, csr_src, N);

        // bufX = LN1(xin + o@Wo + bo)  (fused)  -> fp32 bufX + bf16 hb
        gemm_ln_kernel<<<gLN, blk, 0, stream>>>(qkv, 768, N, 256, BTo_l,
            bo + (size_t)l * 256, xin_f, ln1g + (size_t)l * 256, ln1b + (size_t)l * 256,
            bufX, hb);

        // fout = LN2(h + relu(h@W1+b1)@W2 + b2)  (fully fused FFN)
        float* fout = (l == L - 1) ? (float*)d_out : bufX;
        ffn_fused_kernel<<<gLN, blk, 0, stream>>>(hb, N, BT1_l,
            b1 + (size_t)l * 1024, BT2_l, b2 + (size_t)l * 256, bufX,
            ln2g + (size_t)l * 256, ln2b + (size_t)l * 256,
            fout, (l == L - 1) ? nullptr : xb);

        xin_f = bufX;
    }
}

// Round 4
// 3130.849 us; speedup vs baseline: 1.0979x; 1.0592x over previous
//
#include <hip/hip_runtime.h>
#include <cstdint>
#include <cstddef>

#define D 256
#define H 8
#define DFF 1024

typedef short s16x8 __attribute__((ext_vector_type(8)));
typedef float f32x4 __attribute__((ext_vector_type(4)));

static inline int cdiv(int a, int b) { return (a + b - 1) / b; }

__device__ inline uint16_t f2bf(float x) {
    unsigned u = __float_as_uint(x);
    u += 0x7FFFu + ((u >> 16) & 1u);
    return (uint16_t)(u >> 16);
}
__device__ inline float bf2f(uint16_t h) {
    return __uint_as_float(((unsigned)h) << 16);
}

__device__ inline void gload_lds16(const void* g, void* l) {
    __builtin_amdgcn_global_load_lds(
        (const __attribute__((address_space(1))) void*)g,
        (__attribute__((address_space(3))) void*)l, 16, 0, 0);
}

// counted waitcnt helpers (T4): never drain vmcnt to 0 inside K-loops
__device__ inline void vmcnt0() { asm volatile("s_waitcnt vmcnt(0)" ::: "memory"); }
__device__ inline void vmcnt3() { asm volatile("s_waitcnt vmcnt(3)" ::: "memory"); }
__device__ inline void vmcnt4() { asm volatile("s_waitcnt vmcnt(4)" ::: "memory"); }
__device__ inline void vmcnt5() { asm volatile("s_waitcnt vmcnt(5)" ::: "memory"); }
__device__ inline void lgkm0()  { asm volatile("s_waitcnt lgkmcnt(0)" ::: "memory"); }
// s_barrier is NOT a compiler memory fence: pin scheduling on both sides
// (rule #18 / m152). SB0 is compile-time only.
#define SB0() __builtin_amdgcn_sched_barrier(0)
#define BARF() do { SB0(); __builtin_amdgcn_s_barrier(); SB0(); } while (0)

// ---------------------------------------------------------------------------
// CSR build (graph constant across layers)
// ---------------------------------------------------------------------------
__global__ __launch_bounds__(256) void zero_int_kernel(int* __restrict__ p, int count)
{
    int i = blockIdx.x * blockDim.x + threadIdx.x;
    if (i < count) p[i] = 0;
}

__global__ __launch_bounds__(256) void count_deg_kernel(
    const int* __restrict__ edst, int* __restrict__ deg, int E)
{
    int e = blockIdx.x * blockDim.x + threadIdx.x;
    if (e < E) atomicAdd(&deg[edst[e]], 1);
}

__global__ __launch_bounds__(256) void block_sum_kernel(
    const int* __restrict__ deg, int* __restrict__ bsum, int N)
{
    int t = threadIdx.x;
    int gid = blockIdx.x * 256 + t;
    int val = (gid < N) ? deg[gid] : 0;
    #pragma unroll
    for (int o = 1; o < 64; o <<= 1) val += __shfl_xor(val, o);
    __shared__ int r[4];
    if ((t & 63) == 0) r[t >> 6] = val;
    __syncthreads();
    if (t == 0) bsum[blockIdx.x] = r[0] + r[1] + r[2] + r[3];
}

__global__ __launch_bounds__(256) void scan_bsum_kernel(int* __restrict__ bsum, int nb)
{
    __shared__ int tmp[256];
    int t = threadIdx.x;
    int val = (t < nb) ? bsum[t] : 0;
    tmp[t] = val;
    __syncthreads();
    for (int off = 1; off < 256; off <<= 1) {
        int add = (t >= off) ? tmp[t - off] : 0;
        __syncthreads();
        tmp[t] += add;
        __syncthreads();
    }
    if (t < nb) bsum[t] = tmp[t] - val;
}

__global__ __launch_bounds__(256) void scan_write_kernel(
    const int* __restrict__ deg, const int* __restrict__ bsum,
    int* __restrict__ rowptr, int* __restrict__ cursor, int N)
{
    __shared__ int tmp[256];
    int t = threadIdx.x;
    int gid = blockIdx.x * 256 + t;
    int val = (gid < N) ? deg[gid] : 0;
    tmp[t] = val;
    __syncthreads();
    for (int off = 1; off < 256; off <<= 1) {
        int add = (t >= off) ? tmp[t - off] : 0;
        __syncthreads();
        tmp[t] += add;
        __syncthreads();
    }
    int excl = tmp[t] - val + bsum[blockIdx.x];
    if (gid < N) { rowptr[gid] = excl; cursor[gid] = excl; }
    if (gid == N - 1) rowptr[N] = excl + val;
}

__global__ __launch_bounds__(256) void fill_csr_kernel(
    const int* __restrict__ esrc, const int* __restrict__ edst,
    int* __restrict__ cursor, int* __restrict__ csr_src, int E)
{
    int e = blockIdx.x * blockDim.x + threadIdx.x;
    if (e < E) {
        int pos = atomicAdd(&cursor[edst[e]], 1);
        csr_src[pos] = esrc[e];
    }
}

// ---------------------------------------------------------------------------
// weight transpose+cast: out[c][r] = bf16(in[r][c]); per-z-slice matrices
// ---------------------------------------------------------------------------
__global__ __launch_bounds__(256) void transpose_cast_kernel(
    const float* __restrict__ in, uint16_t* __restrict__ out,
    int R, int C, size_t inLS, size_t outLS)
{
    __shared__ float t[32][33];
    in  += blockIdx.z * inLS;
    out += blockIdx.z * outLS;
    int c0 = blockIdx.x * 32, r0 = blockIdx.y * 32;
    int tx = threadIdx.x, ty = threadIdx.y;  // (32,8)
    #pragma unroll
    for (int i = 0; i < 4; ++i)
        t[ty + i * 8][tx] = in[(size_t)(r0 + ty + i * 8) * C + c0 + tx];
    __syncthreads();
    #pragma unroll
    for (int i = 0; i < 4; ++i)
        out[(size_t)(c0 + ty + i * 8) * R + r0 + tx] = f2bf(t[tx][ty + i * 8]);
}

__global__ __launch_bounds__(256) void cast_f32_bf16_kernel(
    const float* __restrict__ in, uint16_t* __restrict__ out, int n4)
{
    int i = blockIdx.x * blockDim.x + threadIdx.x;
    if (i >= n4) return;
    float4 f = ((const float4*)in)[i];
    uint16_t o0 = f2bf(f.x), o1 = f2bf(f.y), o2 = f2bf(f.z), o3 = f2bf(f.w);
    uint2 pk;
    pk.x = (unsigned)o0 | ((unsigned)o1 << 16);
    pk.y = (unsigned)o2 | ((unsigned)o3 << 16);
    ((uint2*)out)[i] = pk;
}

__global__ __launch_bounds__(256) void build_qkv_bias_kernel(
    const float* __restrict__ bq, float* __restrict__ qb, int total)
{
    int i = blockIdx.x * blockDim.x + threadIdx.x;
    if (i >= total) return;
    int l = i / 768, c = i - l * 768;
    qb[i] = (c < 256) ? bq[l * 256 + c] : 0.f;
}

// ---------------------------------------------------------------------------
// bf16 MFMA GEMM (128x128 tile): used for QKV (Nc=768).
// Double-buffered global_load_lds staging with counted vmcnt (T3/T4).
// All s_barriers wrapped in sched_barrier(0) (BARF) to pin memory ops.
// ---------------------------------------------------------------------------
__global__ __launch_bounds__(256) void gemm_bf16_kernel(
    const uint16_t* __restrict__ A, int lda, int M, int K,
    const uint16_t* __restrict__ BT, int Nc,
    const float* __restrict__ bias,
    uint16_t* __restrict__ Cb, int relu)
{
    __shared__ __align__(16) uint16_t As[2][128 * 32];   // 16 KB
    __shared__ __align__(16) uint16_t Bs[2][128 * 32];   // 16 KB

    const int tid  = threadIdx.x;
    const int lane = tid & 63;
    const int w    = tid >> 6;
    const int wr   = w >> 1, wc = w & 1;
    const int quad = lane >> 4;
    const int l15  = lane & 15;

    // bijective XCD swizzle (m204 form)
    const int nwg = gridDim.x * gridDim.y;
    const int lin = blockIdx.y * gridDim.x + blockIdx.x;
    const int xcd = lin & 7, idx = lin >> 3;
    const int q8 = nwg >> 3, r8 = nwg & 7;
    const int lin2 = (xcd < r8 ? xcd * (q8 + 1) : r8 * (q8 + 1) + (xcd - r8) * q8) + idx;
    const int mt = lin2 % gridDim.x;
    const int nt = lin2 / gridDim.x;

    const int m0 = mt * 128;
    const int n0 = nt * 128;

    f32x4 acc[4][4] = {};

    const int jbase = w * 2;
    const int srow  = lane >> 2;
    const int skc   = (lane & 3) * 8;

    auto stage = [&](int b, int k0) {
        #pragma unroll
        for (int jj = 0; jj < 2; ++jj) {
            int j = jbase + jj;
            int r = j * 16 + srow;
            int gr = m0 + r; if (gr > M - 1) gr = M - 1;
            gload_lds16(A  + (size_t)gr * lda + k0 + skc, &As[b][j * 512]);
            gload_lds16(BT + (size_t)(n0 + r) * K + k0 + skc, &Bs[b][j * 512]);
        }
    };

    const int nsteps = K >> 5;
    stage(0, 0);
    for (int s = 0; s < nsteps; ++s) {
        if (s + 1 < nsteps) { stage((s + 1) & 1, (s + 1) << 5); vmcnt4(); }
        else vmcnt0();
        BARF();
        const int b = s & 1;
        s16x8 af[4], bf[4];
        #pragma unroll
        for (int t = 0; t < 4; ++t) {
            af[t] = *(const s16x8*)&As[b][(wr * 64 + t * 16 + l15) * 32 + quad * 8];
            bf[t] = *(const s16x8*)&Bs[b][(wc * 64 + t * 16 + l15) * 32 + quad * 8];
        }
        #pragma unroll
        for (int i = 0; i < 4; ++i)
            #pragma unroll
            for (int jt = 0; jt < 4; ++jt)
                acc[i][jt] = __builtin_amdgcn_mfma_f32_16x16x32_bf16(
                    af[i], bf[jt], acc[i][jt], 0, 0, 0);
        BARF();
    }

    float bv[4];
    #pragma unroll
    for (int jt = 0; jt < 4; ++jt)
        bv[jt] = bias ? bias[n0 + wc * 64 + jt * 16 + l15] : 0.f;

    #pragma unroll
    for (int i = 0; i < 4; ++i) {
        #pragma unroll
        for (int r = 0; r < 4; ++r) {
            int m = m0 + wr * 64 + i * 16 + quad * 4 + r;
            if (m >= M) continue;
            #pragma unroll
            for (int jt = 0; jt < 4; ++jt) {
                int n = n0 + wc * 64 + jt * 16 + l15;
                float val = acc[i][jt][r] + bv[jt];
                if (relu) val = fmaxf(val, 0.f);
                Cb[(size_t)m * Nc + n] = f2bf(val);
            }
        }
    }
}

// ---------------------------------------------------------------------------
// bf16 MFMA GEMM + fused LayerNorm (Nc == 256). Tile 64Mx256N, 4 waves.
// Double-buffered counted-vmcnt staging. In-place safe for resid==Cf.
// ---------------------------------------------------------------------------
__global__ __launch_bounds__(256) void gemm_ln_kernel(
    const uint16_t* __restrict__ A, int lda, int M, int K,
    const uint16_t* __restrict__ BT,
    const float* __restrict__ bias,
    const float* __restrict__ resid,
    const float* __restrict__ g, const float* __restrict__ b,
    float* __restrict__ Cf, uint16_t* __restrict__ Cb)
{
    __shared__ __align__(16) uint16_t As[2][64 * 32];    //  8 KB
    __shared__ __align__(16) uint16_t Bs[2][256 * 32];   // 32 KB
    __shared__ float sS[64][4];                          //  1 KB
    __shared__ float sQ[64][4];                          //  1 KB

    const int tid  = threadIdx.x;
    const int lane = tid & 63;
    const int w    = tid >> 6;        // wave covers cols w*64..w*64+63
    const int quad = lane >> 4;
    const int l15  = lane & 15;

    const int m0 = blockIdx.x * 64;

    f32x4 acc[4][4] = {};

    auto stage = [&](int bb, int k0) {
        {
            int r = tid >> 2, kc = (tid & 3) * 8;
            int gr = m0 + r; if (gr > M - 1) gr = M - 1;
            gload_lds16(A + (size_t)gr * lda + k0 + kc, &As[bb][tid * 8]);
        }
        #pragma unroll
        for (int i = 0; i < 4; ++i) {
            int slot = i * 256 + tid;
            int n = slot >> 2, kc = (slot & 3) * 8;
            gload_lds16(BT + (size_t)n * K + k0 + kc, &Bs[bb][slot * 8]);
        }
    };

    const int nsteps = K >> 5;
    stage(0, 0);
    for (int s = 0; s < nsteps; ++s) {
        if (s + 1 < nsteps) { stage((s + 1) & 1, (s + 1) << 5); vmcnt5(); }
        else vmcnt0();
        BARF();
        const int bb = s & 1;
        s16x8 af[4], bf[4];
        #pragma unroll
        for (int t = 0; t < 4; ++t) {
            af[t] = *(const s16x8*)&As[bb][(t * 16 + l15) * 32 + quad * 8];
            bf[t] = *(const s16x8*)&Bs[bb][(w * 64 + t * 16 + l15) * 32 + quad * 8];
        }
        #pragma unroll
        for (int i = 0; i < 4; ++i)
            #pragma unroll
            for (int jt = 0; jt < 4; ++jt)
                acc[i][jt] = __builtin_amdgcn_mfma_f32_16x16x32_bf16(
                    af[i], bf[jt], acc[i][jt], 0, 0, 0);
        BARF();
    }

    float bv[4], gv[4], bbv[4];
    #pragma unroll
    for (int jt = 0; jt < 4; ++jt) {
        int n = w * 64 + jt * 16 + l15;
        bv[jt]  = bias[n];
        gv[jt]  = g[n];
        bbv[jt] = b[n];
    }

    #pragma unroll
    for (int i = 0; i < 4; ++i) {
        #pragma unroll
        for (int r = 0; r < 4; ++r) {
            int ml = i * 16 + quad * 4 + r;       // local row 0..63
            int m  = m0 + ml;
            bool valid = (m < M);
            float s = 0.f, s2 = 0.f;
            #pragma unroll
            for (int jt = 0; jt < 4; ++jt) {
                int n = w * 64 + jt * 16 + l15;
                float val = acc[i][jt][r] + bv[jt];
                if (valid) val += resid[(size_t)m * 256 + n];
                acc[i][jt][r] = val;
                s += val;
                s2 += val * val;
            }
            #pragma unroll
            for (int o = 1; o < 16; o <<= 1) {
                s  += __shfl_xor(s, o);
                s2 += __shfl_xor(s2, o);
            }
            if (l15 == 0) { sS[ml][w] = s; sQ[ml][w] = s2; }
        }
    }
    __syncthreads();

    #pragma unroll
    for (int i = 0; i < 4; ++i) {
        #pragma unroll
        for (int r = 0; r < 4; ++r) {
            int ml = i * 16 + quad * 4 + r;
            int m  = m0 + ml;
            if (m >= M) continue;
            float s  = sS[ml][0] + sS[ml][1] + sS[ml][2] + sS[ml][3];
            float s2 = sQ[ml][0] + sQ[ml][1] + sQ[ml][2] + sQ[ml][3];
            float mean = s * (1.f / 256.f);
            float var  = s2 * (1.f / 256.f) - mean * mean;
            float rstd = rsqrtf(var + 1e-5f);
            #pragma unroll
            for (int jt = 0; jt < 4; ++jt) {
                int n = w * 64 + jt * 16 + l15;
                float out = (acc[i][jt][r] - mean) * rstd * gv[jt] + bbv[jt];
                Cf[(size_t)m * 256 + n] = out;
                if (Cb) Cb[(size_t)m * 256 + n] = f2bf(out);
            }
        }
    }
}

// ---------------------------------------------------------------------------
// Fused FFN: out = LN2(resid + relu(h@W1 + b1)@W2 + b2).
// Per block: 64 rows; 8 chunks of DFF=128. Double-buffered counted-vmcnt
// staging for both GEMMs; Ts rows padded to 40 u16.
// LDS: U 32 KB + Ts 20 KB = 52 KB -> 3 blocks/CU.
// ---------------------------------------------------------------------------
__global__ __launch_bounds__(256) void ffn_fused_kernel(
    const uint16_t* __restrict__ A,      // hb [M][256] bf16
    int M,
    const uint16_t* __restrict__ BT1,    // W1^T [1024][256] bf16
    const float* __restrict__ b1,        // [1024]
    const uint16_t* __restrict__ BT2,    // W2^T [256][1024] bf16
    const float* __restrict__ b2,        // [256]
    const float* __restrict__ resid,     // [M][256] fp32
    const float* __restrict__ g, const float* __restrict__ b,
    float* __restrict__ Cf, uint16_t* __restrict__ Cb)
{
    // U per buf: GEMM1 uses u16[0..6144) (As 2048 | Bs1 4096); GEMM2 uses u16[0..8192) (Bs2)
    __shared__ __align__(16) uint16_t U[2][8192];      // 32 KB
    __shared__ __align__(16) uint16_t Ts[4][64][40];   // 20 KB

    const int tid  = threadIdx.x;
    const int lane = tid & 63;
    const int w    = tid >> 6;       // wave: T subtile w (GEMM1), out cols w*64 (GEMM2)
    const int quad = lane >> 4;
    const int l15  = lane & 15;
    const int m0   = blockIdx.x * 64;

    f32x4 acc2[4][4] = {};

    auto stage1 = [&](int bb, int c, int k0) {
        {   // As [64][32]: 256 slots, 1/thread
            int r = tid >> 2, kc = (tid & 3) * 8;
            int gr = m0 + r; if (gr > M - 1) gr = M - 1;
            gload_lds16(A + (size_t)gr * 256 + k0 + kc, &U[bb][tid * 8]);
        }
        #pragma unroll
        for (int i = 0; i < 2; ++i) {   // Bs1 [128][32]: 512 slots, 2/thread
            int slot = i * 256 + tid;
            int n = slot >> 2, kc = (slot & 3) * 8;
            gload_lds16(BT1 + (size_t)(c * 128 + n) * 256 + k0 + kc,
                        &U[bb][2048 + slot * 8]);
        }
    };
    auto stage2 = [&](int bb, int c, int ts) {
        #pragma unroll
        for (int i = 0; i < 4; ++i) {   // Bs2 [256][32]: 1024 slots, 4/thread
            int slot = i * 256 + tid;
            int n = slot >> 2, kc = (slot & 3) * 8;
            gload_lds16(BT2 + (size_t)n * 1024 + c * 128 + ts * 32 + kc,
                        &U[bb][slot * 8]);
        }
    };

    for (int c = 0; c < 8; ++c) {
        f32x4 acc1[4][2] = {};

        // ---- GEMM1: T = h @ W1[:, c*128 .. +128), K=256 in 8 steps ----
        stage1(0, c, 0);
        for (int ks = 0; ks < 8; ++ks) {
            if (ks < 7) { stage1((ks + 1) & 1, c, (ks + 1) << 5); vmcnt3(); }
            else vmcnt0();
            BARF();
            const int bb = ks & 1;
            s16x8 af[4], bf1[2];
            #pragma unroll
            for (int t = 0; t < 4; ++t)
                af[t] = *(const s16x8*)&U[bb][(t * 16 + l15) * 32 + quad * 8];
            #pragma unroll
            for (int jt = 0; jt < 2; ++jt)
                bf1[jt] = *(const s16x8*)&U[bb][2048 + (w * 32 + jt * 16 + l15) * 32 + quad * 8];
            #pragma unroll
            for (int i = 0; i < 4; ++i)
                #pragma unroll
                for (int jt = 0; jt < 2; ++jt)
                    acc1[i][jt] = __builtin_amdgcn_mfma_f32_16x16x32_bf16(
                        af[i], bf1[jt], acc1[i][jt], 0, 0, 0);
            BARF();
        }

        // ---- T epilogue: +b1, relu, bf16 -> Ts subtile w (wave-private) ----
        float bv1[2];
        #pragma unroll
        for (int jt = 0; jt < 2; ++jt)
            bv1[jt] = b1[c * 128 + w * 32 + jt * 16 + l15];
        #pragma unroll
        for (int i = 0; i < 4; ++i)
            #pragma unroll
            for (int r = 0; r < 4; ++r) {
                int ml = i * 16 + quad * 4 + r;
                #pragma unroll
                for (int jt = 0; jt < 2; ++jt) {
                    float val = acc1[i][jt][r] + bv1[jt];
                    val = fmaxf(val, 0.f);
                    Ts[w][ml][jt * 16 + l15] = f2bf(val);
                }
            }
        lgkm0();
        BARF();   // Ts visible to all waves

        // ---- GEMM2: acc2 += T @ W2[c*128 .. +128, :), K=128 in 4 steps ----
        stage2(0, c, 0);
        for (int ts = 0; ts < 4; ++ts) {
            if (ts < 3) { stage2((ts + 1) & 1, c, ts + 1); vmcnt4(); }
            else vmcnt0();
            BARF();
            const int bb = ts & 1;
            s16x8 af2[4], bf2[4];
            #pragma unroll
            for (int i = 0; i < 4; ++i)
                af2[i] = *(const s16x8*)&Ts[ts][i * 16 + l15][quad * 8];
            #pragma unroll
            for (int jt = 0; jt < 4; ++jt)
                bf2[jt] = *(const s16x8*)&U[bb][(w * 64 + jt * 16 + l15) * 32 + quad * 8];
            #pragma unroll
            for (int i = 0; i < 4; ++i)
                #pragma unroll
                for (int jt = 0; jt < 4; ++jt)
                    acc2[i][jt] = __builtin_amdgcn_mfma_f32_16x16x32_bf16(
                        af2[i], bf2[jt], acc2[i][jt], 0, 0, 0);
            BARF();
        }
    }

    // ---- LN epilogue (stats alias the free staging buffer U) ----
    float* sS = (float*)&U[0][0];      // [64][4]
    float* sQ = (float*)&U[0][512];    // [64][4]

    float bv[4], gv[4], bbv[4];
    #pragma unroll
    for (int jt = 0; jt < 4; ++jt) {
        int n = w * 64 + jt * 16 + l15;
        bv[jt]  = b2[n];
        gv[jt]  = g[n];
        bbv[jt] = b[n];
    }

    #pragma unroll
    for (int i = 0; i < 4; ++i) {
        #pragma unroll
        for (int r = 0; r < 4; ++r) {
            int ml = i * 16 + quad * 4 + r;       // local row 0..63
            int m  = m0 + ml;
            bool valid = (m < M);
            float s = 0.f, s2 = 0.f;
            #pragma unroll
            for (int jt = 0; jt < 4; ++jt) {
                float val = acc2[i][jt][r] + bv[jt];
                if (valid) val += resid[(size_t)m * 256 + w * 64 + jt * 16 + l15];
                acc2[i][jt][r] = val;
                s += val;
                s2 += val * val;
            }
            #pragma unroll
            for (int o = 1; o < 16; o <<= 1) {
                s  += __shfl_xor(s, o);
                s2 += __shfl_xor(s2, o);
            }
            if (l15 == 0) { sS[ml * 4 + w] = s; sQ[ml * 4 + w] = s2; }
        }
    }
    __syncthreads();

    #pragma unroll
    for (int i = 0; i < 4; ++i) {
        #pragma unroll
        for (int r = 0; r < 4; ++r) {
            int ml = i * 16 + quad * 4 + r;
            int m  = m0 + ml;
            if (m >= M) continue;
            float s  = sS[ml * 4 + 0] + sS[ml * 4 + 1] + sS[ml * 4 + 2] + sS[ml * 4 + 3];
            float s2 = sQ[ml * 4 + 0] + sQ[ml * 4 + 1] + sQ[ml * 4 + 2] + sQ[ml * 4 + 3];
            float mean = s * (1.f / 256.f);
            float var  = s2 * (1.f / 256.f) - mean * mean;
            float rstd = rsqrtf(var + 1e-5f);
            #pragma unroll
            for (int jt = 0; jt < 4; ++jt) {
                int n = w * 64 + jt * 16 + l15;
                float out = (acc2[i][jt][r] - mean) * rstd * gv[jt] + bbv[jt];
                Cf[(size_t)m * 256 + n] = out;
                if (Cb) Cb[(size_t)m * 256 + n] = f2bf(out);
            }
        }
    }
}

// ---------------------------------------------------------------------------
// Fused per-node attention: one wave per dst node; qkv bf16 [N][768] (q|k|v).
// ILP-2 edge unroll; fp32 accumulation; o in-place over q slice.
// (r0 body: gather is memory-system-bound; ILP-4+scalarize regressed.)
// ---------------------------------------------------------------------------
__global__ __launch_bounds__(256) void node_attn_kernel(
    uint16_t* __restrict__ qkv,
    const int* __restrict__ rowptr, const int* __restrict__ csr_src, int N)
{
    int node = (blockIdx.x * blockDim.x + threadIdx.x) >> 6;
    int lane = threadIdx.x & 63;
    if (node >= N) return;

    uint16_t* qp = qkv + (size_t)node * 768 + lane * 4;
    uint2 qu = *(const uint2*)qp;
    float q0 = bf2f((uint16_t)(qu.x & 0xFFFF)), q1 = bf2f((uint16_t)(qu.x >> 16));
    float q2 = bf2f((uint16_t)(qu.y & 0xFFFF)), q3 = bf2f((uint16_t)(qu.y >> 16));

    float a0 = 0.f, a1 = 0.f, a2 = 0.f, a3 = 0.f, zacc = 0.f;
    const float inv_sqrt_dk = 0.17677669529663687f;  // 1/sqrt(32)

    int beg = rowptr[node], end = rowptr[node + 1];
    int i = beg;
    for (; i + 1 < end; i += 2) {
        int s0 = csr_src[i], s1 = csr_src[i + 1];
        const uint16_t* b0 = qkv + (size_t)s0 * 768;
        const uint16_t* b1 = qkv + (size_t)s1 * 768;
        uint2 ku0 = *(const uint2*)(b0 + 256 + lane * 4);
        uint2 ku1 = *(const uint2*)(b1 + 256 + lane * 4);
        uint2 vu0 = *(const uint2*)(b0 + 512 + lane * 4);
        uint2 vu1 = *(const uint2*)(b1 + 512 + lane * 4);

        float p0 = bf2f((uint16_t)(ku0.x & 0xFFFF)) * q0
                 + bf2f((uint16_t)(ku0.x >> 16))   * q1
                 + bf2f((uint16_t)(ku0.y & 0xFFFF)) * q2
                 + bf2f((uint16_t)(ku0.y >> 16))   * q3;
        float p1 = bf2f((uint16_t)(ku1.x & 0xFFFF)) * q0
                 + bf2f((uint16_t)(ku1.x >> 16))   * q1
                 + bf2f((uint16_t)(ku1.y & 0xFFFF)) * q2
                 + bf2f((uint16_t)(ku1.y >> 16))   * q3;
        p0 += __shfl_xor(p0, 1); p1 += __shfl_xor(p1, 1);
        p0 += __shfl_xor(p0, 2); p1 += __shfl_xor(p1, 2);
        p0 += __shfl_xor(p0, 4); p1 += __shfl_xor(p1, 4);
        float sc0 = __expf(fminf(fmaxf(p0 * inv_sqrt_dk, -5.f), 5.f));
        float sc1 = __expf(fminf(fmaxf(p1 * inv_sqrt_dk, -5.f), 5.f));

        a0 += bf2f((uint16_t)(vu0.x & 0xFFFF)) * sc0;
        a1 += bf2f((uint16_t)(vu0.x >> 16))   * sc0;
        a2 += bf2f((uint16_t)(vu0.y & 0xFFFF)) * sc0;
        a3 += bf2f((uint16_t)(vu0.y >> 16))   * sc0;
        zacc += sc0;
        a0 += bf2f((uint16_t)(vu1.x & 0xFFFF)) * sc1;
        a1 += bf2f((uint16_t)(vu1.x >> 16))   * sc1;
        a2 += bf2f((uint16_t)(vu1.y & 0xFFFF)) * sc1;
        a3 += bf2f((uint16_t)(vu1.y >> 16))   * sc1;
        zacc += sc1;
    }
    if (i < end) {
        int s = csr_src[i];
        const uint16_t* base = qkv + (size_t)s * 768;
        uint2 ku = *(const uint2*)(base + 256 + lane * 4);
        float p = bf2f((uint16_t)(ku.x & 0xFFFF)) * q0
                + bf2f((uint16_t)(ku.x >> 16))   * q1
                + bf2f((uint16_t)(ku.y & 0xFFFF)) * q2
                + bf2f((uint16_t)(ku.y >> 16))   * q3;
        p += __shfl_xor(p, 1);
        p += __shfl_xor(p, 2);
        p += __shfl_xor(p, 4);
        float sc = __expf(fminf(fmaxf(p * inv_sqrt_dk, -5.f), 5.f));
        uint2 vu = *(const uint2*)(base + 512 + lane * 4);
        a0 += bf2f((uint16_t)(vu.x & 0xFFFF)) * sc;
        a1 += bf2f((uint16_t)(vu.x >> 16))   * sc;
        a2 += bf2f((uint16_t)(vu.y & 0xFFFF)) * sc;
        a3 += bf2f((uint16_t)(vu.y >> 16))   * sc;
        zacc += sc;
    }
    float inv = 1.f / zacc;
    uint2 pk;
    pk.x = (unsigned)f2bf(a0 * inv) | ((unsigned)f2bf(a1 * inv) << 16);
    pk.y = (unsigned)f2bf(a2 * inv) | ((unsigned)f2bf(a3 * inv) << 16);
    *(uint2*)qp = pk;
}

// ---------------------------------------------------------------------------
extern "C" void kernel_launch(void* const* d_in, const int* in_sizes, int n_in,
                              void* d_out, int out_size, void* d_ws, size_t ws_size,
                              hipStream_t stream)
{
    const float* x0   = (const float*)d_in[0];
    const int* esrc   = (const int*)d_in[1];
    const int* edst   = (const int*)d_in[2];
    const float* Wq   = (const float*)d_in[3];
    const float* bq   = (const float*)d_in[4];
    const float* Wk   = (const float*)d_in[5];
    const float* Wv   = (const float*)d_in[6];
    const float* Wo   = (const float*)d_in[7];
    const float* bo   = (const float*)d_in[8];
    const float* ln1g = (const float*)d_in[9];
    const float* ln1b = (const float*)d_in[10];
    const float* W1   = (const float*)d_in[11];
    const float* b1   = (const float*)d_in[12];
    const float* W2   = (const float*)d_in[13];
    const float* b2   = (const float*)d_in[14];
    const float* ln2g = (const float*)d_in[15];
    const float* ln2b = (const float*)d_in[16];

    const int N = in_sizes[0] / D;
    const int E = in_sizes[1];
    const int L = in_sizes[3] / (D * D);
    const size_t ND = (size_t)N * D;

    // ---- workspace layout ----
    char* p = (char*)d_ws;
    float* bufX = (float*)p;         p += ND * 4;            // fp32 residual stream
    uint16_t* xb  = (uint16_t*)p;    p += ND * 2;            // bf16 x (QKV input)
    uint16_t* qkv = (uint16_t*)p;    p += (size_t)N * 768 * 2;
    uint16_t* hb  = (uint16_t*)p;    p += ND * 2;            // bf16 h (FFN input)
    uint16_t* BTqkv = (uint16_t*)p;  p += (size_t)L * 768 * 256 * 2;
    uint16_t* BTo   = (uint16_t*)p;  p += (size_t)L * 256 * 256 * 2;
    uint16_t* BT1   = (uint16_t*)p;  p += (size_t)L * 1024 * 256 * 2;
    uint16_t* BT2   = (uint16_t*)p;  p += (size_t)L * 256 * 1024 * 2;
    float* qbias    = (float*)p;     p += (size_t)L * 768 * 4;
    int* rowptr  = (int*)p;          p += (size_t)(N + 1) * 4;
    int* cursor  = (int*)p;          p += (size_t)N * 4;
    int* deg     = cursor;
    int* csr_src = (int*)p;          p += (size_t)E * 4;
    int* bsum    = (int*)p;

    const int nb = cdiv(N, 256);
    dim3 blk(256);
    int edgeBlocks = cdiv(E, 256);
    int nodeBlocks = cdiv(N, 4);

    // ---- one-time setup ----
    dim3 tb(32, 8);
    transpose_cast_kernel<<<dim3(8, 8, L), tb, 0, stream>>>(Wq, BTqkv, 256, 256, (size_t)65536, (size_t)768 * 256);
    transpose_cast_kernel<<<dim3(8, 8, L), tb, 0, stream>>>(Wk, BTqkv + 256 * 256, 256, 256, (size_t)65536, (size_t)768 * 256);
    transpose_cast_kernel<<<dim3(8, 8, L), tb, 0, stream>>>(Wv, BTqkv + 512 * 256, 256, 256, (size_t)65536, (size_t)768 * 256);
    transpose_cast_kernel<<<dim3(8, 8, L), tb, 0, stream>>>(Wo, BTo, 256, 256, (size_t)65536, (size_t)65536);
    transpose_cast_kernel<<<dim3(32, 8, L), tb, 0, stream>>>(W1, BT1, 256, 1024, (size_t)262144, (size_t)262144);
    transpose_cast_kernel<<<dim3(8, 32, L), tb, 0, stream>>>(W2, BT2, 1024, 256, (size_t)262144, (size_t)262144);
    build_qkv_bias_kernel<<<cdiv(L * 768, 256), blk, 0, stream>>>(bq, qbias, L * 768);
    cast_f32_bf16_kernel<<<cdiv((int)(ND / 4), 256), blk, 0, stream>>>(x0, xb, (int)(ND / 4));

    zero_int_kernel<<<cdiv(N, 256), blk, 0, stream>>>(deg, N);
    count_deg_kernel<<<edgeBlocks, blk, 0, stream>>>(edst, deg, E);
    block_sum_kernel<<<nb, blk, 0, stream>>>(deg, bsum, N);
    scan_bsum_kernel<<<1, blk, 0, stream>>>(bsum, nb);
    scan_write_kernel<<<nb, blk, 0, stream>>>(deg, bsum, rowptr, cursor, N);
    fill_csr_kernel<<<edgeBlocks, blk, 0, stream>>>(esrc, edst, cursor, csr_src, E);

    const int Mt128 = cdiv(N, 128);
    const int Mt64  = cdiv(N, 64);
    dim3 gQKV(Mt128, 768 / 128);
    dim3 gLN(Mt64, 1);

    for (int l = 0; l < L; ++l) {
        const uint16_t* BTqkv_l = BTqkv + (size_t)l * 768 * 256;
        const uint16_t* BTo_l   = BTo + (size_t)l * 65536;
        const uint16_t* BT1_l   = BT1 + (size_t)l * 262144;
        const uint16_t* BT2_l   = BT2 + (size_t)l * 262144;
        const float* xin_f = (l == 0) ? x0 : bufX;

        // qkv = xb @ [Wq|Wk|Wv] + [bq|0|0]   (bf16, interleaved per node)
        gemm_bf16_kernel<<<gQKV, blk, 0, stream>>>(xb, 256, N, 256, BTqkv_l, 768,
            qbias + (size_t)l * 768, qkv, 0);

        // o (over q slice) = softmax-weighted aggregate
        node_attn_kernel<<<nodeBlocks, blk, 0, stream>>>(qkv, rowptr, csr_src, N);

        // bufX = LN1(xin + o@Wo + bo)  (fused)  -> fp32 bufX + bf16 hb
        gemm_ln_kernel<<<gLN, blk, 0, stream>>>(qkv, 768, N, 256, BTo_l,
            bo + (size_t)l * 256, xin_f, ln1g + (size_t)l * 256, ln1b + (size_t)l * 256,
            bufX, hb);

        // fout = LN2(h + relu(h@W1+b1)@W2 + b2)  (fully fused FFN)
        float* fout = (l == L - 1) ? (float*)d_out : bufX;
        ffn_fused_kernel<<<gLN, blk, 0, stream>>>(hb, N, BT1_l,
            b1 + (size_t)l * 1024, BT2_l, b2 + (size_t)l * 256, bufX,
            ln2g + (size_t)l * 256, ln2b + (size_t)l * 256,
            fout, (l == L - 1) ? nullptr : xb);

        xin_f = bufX;
    }
}